// Round 14
// baseline (314.308 us; speedup 1.0000x reference)
//
#include <hip/hip_runtime.h>

typedef unsigned short u16;
typedef unsigned int   u32;

#define L_SEQ    2048
#define D_MODEL  1024
#define D_STATE  128
#define D_INNER  2048
#define NHEADS   32
#define HEADDIM  64
#define CONV_DIM 2304
#define D_IN_PROJ 4384
#define EPSF     1e-5f
#define QC       128        // SSD chunk length
#define NCH      16         // chunks = L_SEQ/QC

using frag  = __attribute__((ext_vector_type(8))) short;
using f32x4 = __attribute__((ext_vector_type(4))) float;
typedef __attribute__((ext_vector_type(8))) unsigned short u16x8;

__device__ __forceinline__ u16 f2bf(float f) {
  u32 u = __float_as_uint(f);
  return (u16)((u + 0x7fffu + ((u >> 16) & 1u)) >> 16);
}
__device__ __forceinline__ float bf2f(u16 u) {
  return __uint_as_float(((u32)u) << 16);
}
__device__ __forceinline__ void async16(const void* g, void* l) {
  __builtin_amdgcn_global_load_lds((const __attribute__((address_space(1))) u32*)g,
                                   (__attribute__((address_space(3))) u32*)l, 16, 0, 0);
}

// ---------------- fused fp32->bf16 converts + W1-tail zero + nw-fold into W2 ----------------
__global__ __launch_bounds__(256) void k_cvt_all(const float* __restrict__ x,
                                                 u16* __restrict__ xb,
                                                 const float* __restrict__ w1,
                                                 u16* __restrict__ w1b,
                                                 const float* __restrict__ w2,
                                                 u16* __restrict__ w2b,
                                                 const float* __restrict__ nw) {
  int bid = blockIdx.x;
  int t = threadIdx.x;
  if (bid >= 12576 && bid < 14624) {
    // W2 path: fold norm_w (per inner-dim column) into the weight
    int i = (bid - 12576) * 256 + t;
    float4 v = ((const float4*)w2)[i];
    float4 wv = *(const float4*)(nw + ((i * 4) & (D_INNER - 1)));
    ushort4 o;
    o.x = f2bf(v.x * wv.x); o.y = f2bf(v.y * wv.y);
    o.z = f2bf(v.z * wv.z); o.w = f2bf(v.w * wv.w);
    ((ushort4*)w2b)[i] = o;
    return;
  }
  const float* src;
  u16* dst;
  int i;
  if (bid < 8192)       { i = bid * 256 + t;          src = x;  dst = xb;  }
  else if (bid < 12576) { i = (bid - 8192) * 256 + t; src = w1; dst = w1b; }
  else {  // zero pad rows 4384..4479 of w1b
    i = (bid - 14624) * 256 + t;
    ((ushort4*)(w1b + (size_t)4384 * 1024))[i] = ushort4{0, 0, 0, 0};
    return;
  }
  float4 v = ((const float4*)src)[i];
  ushort4 o;
  o.x = f2bf(v.x); o.y = f2bf(v.y); o.z = f2bf(v.z); o.w = f2bf(v.w);
  ((ushort4*)dst)[i] = o;
}

// ====== unified GEMM (champion + XCD swizzle): 128x128 tile, 4 waves, 2-phase dbuf, vmcnt(4).
// MODE 0: out = rowscale * gemm + resid (out_proj).  MODE 1: bf16 out + f32 dt side-copy.
template <int MODE>
__global__ __launch_bounds__(256) void k_gemm(const u16* __restrict__ A,
                                              const u16* __restrict__ B, int K,
                                              int Nvalid, int ldc,
                                              u16* __restrict__ Cb,
                                              float* __restrict__ Cf,
                                              const float* __restrict__ resid,
                                              float* __restrict__ Cdt,
                                              const float* __restrict__ sumsq) {
  __shared__ __attribute__((aligned(16))) u16 As[2][128 * 32];
  __shared__ __attribute__((aligned(16))) u16 Bs[2][128 * 32];
  const int tid = threadIdx.x;
  const int lane = tid & 63;
  const int wid = tid >> 6;          // 0..3
  const int wm = wid >> 1, wn = wid & 1;
  // XCD-aware bijective block swizzle (nwg % 8 == 0 for both call sites):
  // XCD k (= dispatch%8) gets a contiguous span of tiles -> per-XCD L2 B-panel residency.
  int gx = gridDim.x;
  int nwg = gx * gridDim.y;
  int d = blockIdx.x + gx * blockIdx.y;
  int dd = (nwg & 7) ? d : ((d & 7) * (nwg >> 3) + (d >> 3));
  const int m0 = (dd % gx) * 128, n0 = (dd / gx) * 128;

  f32x4 acc[4][4];
#pragma unroll
  for (int i = 0; i < 4; ++i)
#pragma unroll
    for (int j = 0; j < 4; ++j) acc[i][j] = f32x4{0.f, 0.f, 0.f, 0.f};

  const char* gA[2]; const char* gB[2];
  int cbo[2];
#pragma unroll
  for (int j = 0; j < 2; ++j) {
    int base = (wid * 2 + j) * 1024;
    int p = base + lane * 16;
    int row = p >> 6;
    int colb = p & 63;
    gA[j] = (const char*)A + ((size_t)(m0 + row) * K) * 2 + colb;
    gB[j] = (const char*)B + ((size_t)(n0 + row) * K) * 2 + colb;
    cbo[j] = base;
  }

#define STAGE(bufi, kt) do { size_t kb = (size_t)(kt) * 64; \
    async16(gA[0] + kb, (char*)As[bufi] + cbo[0]); \
    async16(gA[1] + kb, (char*)As[bufi] + cbo[1]); \
    async16(gB[0] + kb, (char*)Bs[bufi] + cbo[0]); \
    async16(gB[1] + kb, (char*)Bs[bufi] + cbo[1]); } while (0)

  const int kg = (lane >> 4) * 16;
  const int rr = wm * 64 + (lane & 15);
  const int cc = wn * 64 + (lane & 15);

  STAGE(0, 0);
  const int nt = K >> 5;
  for (int t = 0; t < nt; ++t) {
    const int cur = t & 1;
    if (t + 1 < nt) {
      STAGE(cur ^ 1, t + 1);
      asm volatile("s_waitcnt vmcnt(4)" ::: "memory");  // oldest 4 (cur buf) landed
    } else {
      asm volatile("s_waitcnt vmcnt(0)" ::: "memory");
    }
    asm volatile("s_barrier" ::: "memory");
    frag af[4], bfr[4];
#pragma unroll
    for (int mi = 0; mi < 4; ++mi)
      af[mi] = *(const frag*)((const char*)As[cur] + (rr + mi * 16) * 64 + kg);
#pragma unroll
    for (int ni = 0; ni < 4; ++ni)
      bfr[ni] = *(const frag*)((const char*)Bs[cur] + (cc + ni * 16) * 64 + kg);
#pragma unroll
    for (int mi = 0; mi < 4; ++mi)
#pragma unroll
      for (int ni = 0; ni < 4; ++ni)
        acc[mi][ni] = __builtin_amdgcn_mfma_f32_16x16x32_bf16(af[mi], bfr[ni],
                                                              acc[mi][ni], 0, 0, 0);
    asm volatile("s_waitcnt lgkmcnt(0)" ::: "memory");
    asm volatile("s_barrier" ::: "memory");
  }
#undef STAGE

  const int er = (lane >> 4) * 4;
  const int ec = lane & 15;
  if (MODE == 1) {
#pragma unroll
    for (int mi = 0; mi < 4; ++mi) {
#pragma unroll
      for (int ni = 0; ni < 4; ++ni) {
        int col = n0 + wn * 64 + ni * 16 + ec;
        if (col < Nvalid) {
#pragma unroll
          for (int r = 0; r < 4; ++r) {
            int row = m0 + wm * 64 + mi * 16 + er + r;
            size_t off = (size_t)row * ldc + col;
            float v = acc[mi][ni][r];
            Cb[off] = f2bf(v);
            if (col >= D_INNER + CONV_DIM)
              Cdt[(size_t)row * NHEADS + (col - D_INNER - CONV_DIM)] = v;
          }
        }
      }
    }
  } else {
#pragma unroll
    for (int mi = 0; mi < 4; ++mi) {
#pragma unroll
      for (int r = 0; r < 4; ++r) {
        int row = m0 + wm * 64 + mi * 16 + er + r;
        float sc = rsqrtf(sumsq[row] * (1.f / D_INNER) + EPSF);
#pragma unroll
        for (int ni = 0; ni < 4; ++ni) {
          int col = n0 + wn * 64 + ni * 16 + ec;
          size_t off = (size_t)row * ldc + col;
          Cf[off] = acc[mi][ni][r] * sc + resid[off];
        }
      }
    }
  }
}

// ---------------- depthwise conv(4)+silu (4-l strips) AND dt/cumsum (merged) ----------------
__global__ __launch_bounds__(256) void k_convcum(const u16* __restrict__ zxb,
                                                 const float* __restrict__ cw,
                                                 const float* __restrict__ cb,
                                                 u16* __restrict__ xcb,
                                                 u16* __restrict__ bcb,
                                                 const float* __restrict__ dtf,
                                                 const float* __restrict__ dtb,
                                                 const float* __restrict__ alog,
                                                 float* __restrict__ dtv,
                                                 float* __restrict__ cumv) {
  int bid = blockIdx.x;
  if (bid < 2048) {
    // conv strip: 4 consecutive l, 7-row register window (halo loaded once)
    int b = bid >> 9;                 // 512 strips per batch
    int l0 = (bid & 511) * 4;
    size_t rowbase = (size_t)b * L_SEQ + l0;
    for (int g = threadIdx.x; g < CONV_DIM / 4; g += 256) {
      int c = g * 4;
      float4 w0 = ((const float4*)cw)[c + 0];
      float4 w1 = ((const float4*)cw)[c + 1];
      float4 w2 = ((const float4*)cw)[c + 2];
      float4 w3 = ((const float4*)cw)[c + 3];
      float4 bias = *(const float4*)(cb + c);
      ushort4 xv[7];
#pragma unroll
      for (int k = 0; k < 7; ++k) {
        int lm = l0 - 3 + k;
        xv[k] = (lm >= 0)
            ? *(const ushort4*)(zxb + (rowbase + (k - 3)) * D_IN_PROJ + D_INNER + c)
            : ushort4{0, 0, 0, 0};
      }
#pragma unroll
      for (int dl = 0; dl < 4; ++dl) {
        float a0 = bias.x, a1 = bias.y, a2 = bias.z, a3 = bias.w;
#pragma unroll
        for (int k = 0; k < 4; ++k) {
          ushort4 v = xv[dl + k];     // row l0+dl-3+k  (zeros below l=0)
          a0 = fmaf(bf2f(v.x), (&w0.x)[k], a0);
          a1 = fmaf(bf2f(v.y), (&w1.x)[k], a1);
          a2 = fmaf(bf2f(v.z), (&w2.x)[k], a2);
          a3 = fmaf(bf2f(v.w), (&w3.x)[k], a3);
        }
        a0 = a0 / (1.f + __expf(-a0));
        a1 = a1 / (1.f + __expf(-a1));
        a2 = a2 / (1.f + __expf(-a2));
        a3 = a3 / (1.f + __expf(-a3));
        ushort4 o;
        o.x = f2bf(a0); o.y = f2bf(a1); o.z = f2bf(a2); o.w = f2bf(a3);
        size_t row = rowbase + dl;
        if (c < D_INNER) {
          *(ushort4*)(xcb + row * D_INNER + c) = o;
        } else {
          *(ushort4*)(bcb + row * 256 + (c - D_INNER)) = o;
        }
      }
    }
    return;
  }
  // dt + in-chunk inclusive cumsum (blocks 2048..4095, threads 0..127 active)
  int cb_ = bid - 2048;            // bh*16 + c
  int c = cb_ & (NCH - 1);
  int bh = cb_ >> 4;
  int h = bh & 31, b = bh >> 5;
  int t = threadIdx.x;
  float x = 0.f, dt = 0.f;
  if (t < 128) {
    int l = c * QC + t;
    float raw = dtf[((size_t)(b * L_SEQ + l)) * NHEADS + h] + dtb[h];
    dt = raw > 20.f ? raw : log1pf(expf(raw));
    float A = -expf(alog[h]);
    x = dt * A;
    int lane = t & 63;
#pragma unroll
    for (int off = 1; off < 64; off <<= 1) {
      float up = __shfl_up(x, off);
      if (lane >= off) x += up;
    }
  }
  __shared__ float wtot;
  if (t == 63) wtot = x;
  __syncthreads();
  if (t < 128) {
    if (t >= 64) x += wtot;
    size_t o = (size_t)bh * L_SEQ + c * QC + t;
    dtv[o] = dt;
    cumv[o] = x;
  }
}

// ========= merged SSD stage 1: k_states (bid<2048) + k_g halves (bid>=2048) =========
__global__ __launch_bounds__(256) void k_ssd1(const u16* __restrict__ xcb,
                                              const u16* __restrict__ bcb,
                                              const float* __restrict__ dtv,
                                              const float* __restrict__ cumv,
                                              u16* __restrict__ SH,
                                              u16* __restrict__ Gb,
                                              float* __restrict__ sumsq) {
  __shared__ __attribute__((aligned(16))) char smem[52736];
  int bid = blockIdx.x;
  int tid = threadIdx.x, lane = tid & 63, wid = tid >> 6;
  int wm = wid >> 1, wn = wid & 1;
  const int er = (lane >> 4) * 4;
  const int ec = lane & 15;

  if (bid < 2048) {
    // -------- states path --------
    u16* XT = (u16*)smem;                    // [64][136]
    u16* BW = (u16*)(smem + 17408);          // [128][136]
    float* wlds = (float*)(smem + 52224);    // [128]
    int c = bid & (NCH - 1);
    int bh = bid >> 4;
    int h = bh & 31, b = bh >> 5;
    int l0 = c * QC;
    size_t bhl = (size_t)bh * L_SEQ + l0;
    if (tid < 128) {
      float ce = cumv[bhl + 127];
      wlds[tid] = __expf(ce - cumv[bhl + tid]) * dtv[bhl + tid];
    }
    const int jrow = tid & 127;
    const u16* xbase = xcb + ((size_t)(b * L_SEQ + l0)) * D_INNER + h * HEADDIM;
    {
      int sb = (tid >> 7) * 4;
#pragma unroll
      for (int s = 0; s < 4; ++s) {
        int seg = sb + s;
        u16x8 xv = *(const u16x8*)(xbase + (size_t)jrow * D_INNER + seg * 8);
#pragma unroll
        for (int k = 0; k < 8; ++k) XT[(seg * 8 + k) * 136 + jrow] = xv[k];
      }
    }
    __syncthreads();
    const u16* bbase = bcb + (size_t)(b * L_SEQ + l0) * 256;
    {
      int sb = (tid >> 7) * 8;
      float w = wlds[jrow];
#pragma unroll
      for (int s = 0; s < 8; ++s) {
        int seg = sb + s;
        u16x8 bv = *(const u16x8*)(bbase + (size_t)jrow * 256 + seg * 8);
#pragma unroll
        for (int k = 0; k < 8; ++k)
          BW[(seg * 8 + k) * 136 + jrow] = f2bf(bf2f(bv[k]) * w);
      }
    }
    __syncthreads();
    f32x4 acc[2][4];
#pragma unroll
    for (int i = 0; i < 2; ++i)
#pragma unroll
      for (int j = 0; j < 4; ++j) acc[i][j] = f32x4{0.f, 0.f, 0.f, 0.f};
    int rr = wm * 32 + (lane & 15);
    int cc = wn * 64 + (lane & 15);
    __builtin_amdgcn_s_setprio(1);
#pragma unroll
    for (int kk = 0; kk < 4; ++kk) {
      int ko = kk * 32 + (lane >> 4) * 8;
      frag af[2], bfr[4];
#pragma unroll
      for (int mi = 0; mi < 2; ++mi)
        af[mi] = *(const frag*)&XT[(rr + mi * 16) * 136 + ko];
#pragma unroll
      for (int ni = 0; ni < 4; ++ni)
        bfr[ni] = *(const frag*)&BW[(cc + ni * 16) * 136 + ko];
#pragma unroll
      for (int mi = 0; mi < 2; ++mi)
#pragma unroll
        for (int ni = 0; ni < 4; ++ni)
          acc[mi][ni] = __builtin_amdgcn_mfma_f32_16x16x32_bf16(af[mi], bfr[ni],
                                                                acc[mi][ni], 0, 0, 0);
    }
    __builtin_amdgcn_s_setprio(0);
    u16* sbase = SH + ((size_t)(bh * NCH + c)) * (64 * 128);
#pragma unroll
    for (int mi = 0; mi < 2; ++mi)
#pragma unroll
      for (int ni = 0; ni < 4; ++ni)
#pragma unroll
        for (int r = 0; r < 4; ++r) {
          int p = wm * 32 + mi * 16 + er + r;
          int n = wn * 64 + ni * 16 + ec;
          sbase[(size_t)p * 128 + n] = f2bf(acc[mi][ni][r]);
        }
  } else {
    // -------- G path: half of one (b,chunk): G rows half*64..+63 --------
    u16* Cs = (u16*)smem;                    // [64][136]
    u16* Bs = (u16*)(smem + 17408);          // [128][136]
    int gbid = bid - 2048;                   // (b*16 + c)*2 + half
    if (gbid < 32) sumsq[gbid * 256 + tid] = 0.f;   // zero 8192-row accumulator
    int half = gbid & 1;
    int c = (gbid >> 1) & (NCH - 1);
    int b = gbid >> 5;
    const u16* base = bcb + (size_t)(b * L_SEQ + c * QC) * 256;
    for (int idx = tid; idx < 128 * 16; idx += 256) {
      int j = idx >> 4, seg = idx & 15;
      *(u16x8*)&Bs[j * 136 + seg * 8] = *(const u16x8*)(base + (size_t)j * 256 + seg * 8);
    }
    for (int idx = tid; idx < 64 * 16; idx += 256) {
      int i = idx >> 4, seg = idx & 15;
      *(u16x8*)&Cs[i * 136 + seg * 8] =
          *(const u16x8*)(base + (size_t)(half * 64 + i) * 256 + 128 + seg * 8);
    }
    __syncthreads();
    f32x4 acc[2][4];
#pragma unroll
    for (int i = 0; i < 2; ++i)
#pragma unroll
      for (int j = 0; j < 4; ++j) acc[i][j] = f32x4{0.f, 0.f, 0.f, 0.f};
    int rr = wm * 32 + (lane & 15);
    int cc = wn * 64 + (lane & 15);
    __builtin_amdgcn_s_setprio(1);
#pragma unroll
    for (int kk = 0; kk < 4; ++kk) {
      int ko = kk * 32 + (lane >> 4) * 8;
      frag af[2], bfr[4];
#pragma unroll
      for (int mi = 0; mi < 2; ++mi)
        af[mi] = *(const frag*)&Cs[(rr + mi * 16) * 136 + ko];
#pragma unroll
      for (int ni = 0; ni < 4; ++ni)
        bfr[ni] = *(const frag*)&Bs[(cc + ni * 16) * 136 + ko];
#pragma unroll
      for (int mi = 0; mi < 2; ++mi)
#pragma unroll
        for (int ni = 0; ni < 4; ++ni)
          acc[mi][ni] = __builtin_amdgcn_mfma_f32_16x16x32_bf16(af[mi], bfr[ni],
                                                                acc[mi][ni], 0, 0, 0);
    }
    __builtin_amdgcn_s_setprio(0);
    u16* gbase = Gb + ((size_t)(b * NCH + c)) * 128 * 128;
#pragma unroll
    for (int mi = 0; mi < 2; ++mi)
#pragma unroll
      for (int ni = 0; ni < 4; ++ni)
#pragma unroll
        for (int r = 0; r < 4; ++r) {
          int i = half * 64 + wm * 32 + mi * 16 + er + r;
          int j = wn * 64 + ni * 16 + ec;
          gbase[(size_t)i * 128 + j] = f2bf(acc[mi][ni][r]);
        }
  }
}

// ---------------- inter-chunk chain (in place), prefetched ----------------
__global__ __launch_bounds__(512) void k_chain(u16* __restrict__ SH,
                                               const float* __restrict__ cumv) {
  int bid = blockIdx.x;
  int half = bid & 1;
  int bh = bid >> 1;
  int t = threadIdx.x;
  u16* base = SH + (size_t)bh * NCH * 8192 + half * 4096 + t * 8;
  float H[8];
#pragma unroll
  for (int i = 0; i < 8; ++i) H[i] = 0.f;
  u16x8 s = *(const u16x8*)base;
  float e = __expf(cumv[(size_t)bh * L_SEQ + 127]);
  for (int c = 0; c < NCH; ++c) {
    u16x8 cs = s;
    float ce = e;
    if (c + 1 < NCH) {
      s = *(const u16x8*)(base + (size_t)(c + 1) * 8192);
      e = __expf(cumv[(size_t)bh * L_SEQ + (c + 1) * QC + 127]);
    }
    u16x8 h0;
#pragma unroll
    for (int k = 0; k < 8; ++k) h0[k] = f2bf(H[k]);
    *(u16x8*)(base + (size_t)c * 8192) = h0;
#pragma unroll
    for (int k = 0; k < 8; ++k) H[k] = fmaf(H[k], ce, bf2f(cs[k]));
  }
}

// ---------------- Y = M@X^T + exp(cum_i)*(C@H^T), then FUSED gate ----------------
__global__ __launch_bounds__(256) void k_y(const u16* __restrict__ xcb,
                                           const u16* __restrict__ bcb,
                                           const u16* __restrict__ zxb,
                                           const float* __restrict__ dtv,
                                           const float* __restrict__ cumv,
                                           const u16* __restrict__ Gb,
                                           const u16* __restrict__ SH,
                                           const float* __restrict__ Dp,
                                           u16* __restrict__ ysb,
                                           float* __restrict__ sumsq) {
  __shared__ u16 Abuf[128 * 136];
  __shared__ u16 Bbuf[64 * 136];
  __shared__ float cums[128], dts[128];
  float* rowsq = dts;                 // dts dead after mask phase; reuse for row sums
  int bid = blockIdx.x;
  int c = bid & (NCH - 1);
  int bh = bid >> 4;
  int h = bh & 31, b = bh >> 5;
  int tid = threadIdx.x, lane = tid & 63, wid = tid >> 6;
  int wm = wid >> 1, wn = wid & 1;
  int l0 = c * QC;
  size_t bhl = (size_t)bh * L_SEQ + l0;
  if (tid < 128) { cums[tid] = cumv[bhl + tid]; dts[tid] = dtv[bhl + tid]; }
  const u16* xbase = xcb + ((size_t)(b * L_SEQ + l0)) * D_INNER + h * HEADDIM;
  {
    int jrow = tid & 127;
    int sb = (tid >> 7) * 4;
#pragma unroll
    for (int s = 0; s < 4; ++s) {
      int seg = sb + s;
      u16x8 xv = *(const u16x8*)(xbase + (size_t)jrow * D_INNER + seg * 8);
#pragma unroll
      for (int k = 0; k < 8; ++k) Bbuf[(seg * 8 + k) * 136 + jrow] = xv[k];
    }
  }
  __syncthreads();
  const u16* gbase = Gb + ((size_t)(b * NCH + c)) * 128 * 128;
  for (int idx = tid; idx < 128 * 16; idx += 256) {
    int i = idx >> 4, seg = idx & 15;
    int j0 = seg * 8;
    u16x8 o;
    if (j0 > i) {
#pragma unroll
      for (int k = 0; k < 8; ++k) o[k] = 0;
    } else {
      u16x8 g = *(const u16x8*)(gbase + (size_t)i * 128 + j0);
      float ci = cums[i];
#pragma unroll
      for (int k = 0; k < 8; ++k) {
        int j = j0 + k;
        float m = (j <= i) ? bf2f(g[k]) * __expf(ci - cums[j]) * dts[j] : 0.f;
        o[k] = f2bf(m);
      }
    }
    *(u16x8*)&Abuf[i * 136 + j0] = o;
  }
  __syncthreads();
  f32x4 acc1[4][2], acc2[4][2];
#pragma unroll
  for (int i = 0; i < 4; ++i)
#pragma unroll
    for (int j = 0; j < 2; ++j) {
      acc1[i][j] = f32x4{0.f, 0.f, 0.f, 0.f};
      acc2[i][j] = f32x4{0.f, 0.f, 0.f, 0.f};
    }
  int rr = wm * 64 + (lane & 15);
  int cc = wn * 32 + (lane & 15);
  __builtin_amdgcn_s_setprio(1);
#pragma unroll
  for (int kk = 0; kk < 4; ++kk) {
    int ko = kk * 32 + (lane >> 4) * 8;
    frag af[4], bfr[2];
#pragma unroll
    for (int mi = 0; mi < 4; ++mi)
      af[mi] = *(const frag*)&Abuf[(rr + mi * 16) * 136 + ko];
#pragma unroll
    for (int ni = 0; ni < 2; ++ni)
      bfr[ni] = *(const frag*)&Bbuf[(cc + ni * 16) * 136 + ko];
#pragma unroll
    for (int mi = 0; mi < 4; ++mi)
#pragma unroll
      for (int ni = 0; ni < 2; ++ni)
        acc1[mi][ni] = __builtin_amdgcn_mfma_f32_16x16x32_bf16(af[mi], bfr[ni],
                                                               acc1[mi][ni], 0, 0, 0);
  }
  __builtin_amdgcn_s_setprio(0);
  __syncthreads();
  // capture X values for the epilogue from Bbuf (X^T) BEFORE it is overwritten by H.
  // Bbuf[p*136 + i] = X[row i][p];  2-way bank aliasing only (stride 272B).
  const int er = (lane >> 4) * 4;
  const int ec = lane & 15;
  u16 xr[4][4][2];
#pragma unroll
  for (int mi = 0; mi < 4; ++mi)
#pragma unroll
    for (int r = 0; r < 4; ++r) {
      int i = wm * 64 + mi * 16 + er + r;
#pragma unroll
      for (int ni = 0; ni < 2; ++ni) {
        int p = wn * 32 + ni * 16 + ec;
        xr[mi][r][ni] = Bbuf[p * 136 + i];
      }
    }
  __syncthreads();   // captures complete before overwrite
  const u16* cbase = bcb + (size_t)(b * L_SEQ + l0) * 256 + 128;
  for (int idx = tid; idx < 128 * 16; idx += 256) {
    int i = idx >> 4, seg = idx & 15;
    *(u16x8*)&Abuf[i * 136 + seg * 8] = *(const u16x8*)(cbase + (size_t)i * 256 + seg * 8);
  }
  const u16* hbase = SH + ((size_t)(bh * NCH + c)) * (64 * 128);
  for (int idx = tid; idx < 64 * 16; idx += 256) {
    int p = idx >> 4, seg = idx & 15;
    *(u16x8*)&Bbuf[p * 136 + seg * 8] = *(const u16x8*)(hbase + (size_t)p * 128 + seg * 8);
  }
  __syncthreads();
  if (tid < 128) rowsq[tid] = 0.f;    // dts no longer needed; zero row accumulators
  __builtin_amdgcn_s_setprio(1);
#pragma unroll
  for (int kk = 0; kk < 4; ++kk) {
    int ko = kk * 32 + (lane >> 4) * 8;
    frag af[4], bfr[2];
#pragma unroll
    for (int mi = 0; mi < 4; ++mi)
      af[mi] = *(const frag*)&Abuf[(rr + mi * 16) * 136 + ko];
#pragma unroll
    for (int ni = 0; ni < 2; ++ni)
      bfr[ni] = *(const frag*)&Bbuf[(cc + ni * 16) * 136 + ko];
#pragma unroll
    for (int mi = 0; mi < 4; ++mi)
#pragma unroll
      for (int ni = 0; ni < 2; ++ni)
        acc2[mi][ni] = __builtin_amdgcn_mfma_f32_16x16x32_bf16(af[mi], bfr[ni],
                                                               acc2[mi][ni], 0, 0, 0);
  }
  __builtin_amdgcn_s_setprio(0);
  __syncthreads();                    // rowsq zeroed + all MFMAs done before atomics
  const float Dh = Dp[h];
#pragma unroll
  for (int mi = 0; mi < 4; ++mi)
#pragma unroll
    for (int r = 0; r < 4; ++r) {
      int i = wm * 64 + mi * 16 + er + r;
      size_t grow = (size_t)(b * L_SEQ + l0 + i);
      float e = __expf(cums[i]);
      float part = 0.f;
#pragma unroll
      for (int ni = 0; ni < 2; ++ni) {
        int p = wn * 32 + ni * 16 + ec;
        float acc = acc1[mi][ni][r] + e * acc2[mi][ni][r];
        float xv = bf2f(xr[mi][r][ni]);
        float zz = bf2f(zxb[grow * D_IN_PROJ + h * HEADDIM + p]);
        float val = (acc + Dh * xv) * (zz / (1.f + __expf(-zz)));
        ysb[grow * D_INNER + h * HEADDIM + p] = f2bf(val);
        part += val * val;
      }
      part += __shfl_xor(part, 1);
      part += __shfl_xor(part, 2);
      part += __shfl_xor(part, 4);
      part += __shfl_xor(part, 8);
      if ((lane & 15) == 0) atomicAdd(&rowsq[i], part);
    }
  __syncthreads();
  if (tid < 128) atomicAdd(&sumsq[(size_t)b * L_SEQ + l0 + tid], rowsq[tid]);
}

// ---------------- final LayerNorm (in-place on d_out) ----------------
union F4 { float4 v; float f[4]; };
__global__ __launch_bounds__(256) void k_ln(float* __restrict__ io,
                                            const float* __restrict__ lw,
                                            const float* __restrict__ lb) {
  int row = blockIdx.x;
  int t = threadIdx.x;
  int d0 = t * 4;
  F4 v; v.v = *(const float4*)(io + (size_t)row * D_MODEL + d0);
  float s1 = v.f[0] + v.f[1] + v.f[2] + v.f[3];
  float s2 = v.f[0] * v.f[0] + v.f[1] * v.f[1] + v.f[2] * v.f[2] + v.f[3] * v.f[3];
  __shared__ float r1[4], r2[4];
#pragma unroll
  for (int off = 32; off; off >>= 1) {
    s1 += __shfl_xor(s1, off);
    s2 += __shfl_xor(s2, off);
  }
  if ((t & 63) == 0) { r1[t >> 6] = s1; r2[t >> 6] = s2; }
  __syncthreads();
  float S1 = r1[0] + r1[1] + r1[2] + r1[3];
  float S2 = r2[0] + r2[1] + r2[2] + r2[3];
  float mu = S1 * (1.f / D_MODEL);
  float var = S2 * (1.f / D_MODEL) - mu * mu;
  float inv = rsqrtf(var + EPSF);
  F4 w, bb, o;
  w.v = *(const float4*)(lw + d0);
  bb.v = *(const float4*)(lb + d0);
#pragma unroll
  for (int c = 0; c < 4; ++c) o.f[c] = (v.f[c] - mu) * inv * w.f[c] + bb.f[c];
  *(float4*)(io + (size_t)row * D_MODEL + d0) = o.v;
}

extern "C" void kernel_launch(void* const* d_in, const int* in_sizes, int n_in,
                              void* d_out, int out_size, void* d_ws, size_t ws_size,
                              hipStream_t stream) {
  const float* x    = (const float*)d_in[0];
  const float* w1   = (const float*)d_in[1];
  const float* cw   = (const float*)d_in[2];
  const float* cb   = (const float*)d_in[3];
  const float* dtb  = (const float*)d_in[4];
  const float* alog = (const float*)d_in[5];
  const float* Dp   = (const float*)d_in[6];
  const float* nw   = (const float*)d_in[7];
  const float* w2   = (const float*)d_in[8];
  const float* lw   = (const float*)d_in[9];
  const float* lb   = (const float*)d_in[10];
  float* out = (float*)d_out;
  char* ws = (char*)d_ws;

  // workspace layout (bytes)
  u16*   xb   = (u16*)(ws + 0);            // 8192x1024 bf16  16,777,216
  u16*   w1b  = (u16*)(ws + 16777216);     // 4480x1024 bf16   9,175,040
  u16*   w2b  = (u16*)(ws + 25952256);     // 1024x2048 bf16   4,194,304
  u16*   zxb  = (u16*)(ws + 30146560);     // 8192x4384 bf16  71,827,456
  u16*   xcb  = (u16*)(ws + 101974016);    // 8192x2048 bf16  33,554,432
  float* dtf  = (float*)(ws + 135528448);  // 8192x32 f32      1,048,576
  float* dtv  = (float*)(ws + 136577024);  // 128x2048 f32     1,048,576
  float* cumv = (float*)(ws + 137625600);  // 128x2048 f32     1,048,576
  u16*   ysb  = (u16*)(ws + 138674176);    // 8192x2048 bf16  33,554,432
  u16*   yb   = (u16*)(ws + 172228608);    // 8192x2048 bf16  33,554,432
  u16*   Gb   = (u16*)(ws + 205783040);    // 64x128x128 bf16  4,194,304
  // total: 209,977,344 (proven available)
  if (ws_size < (size_t)209977344) return;

  u16* bcb = (u16*)out;      // d_out as B/C bf16 scratch (8192x256) until out_proj
  u16* SH  = yb;             // chunk states bf16 [bh][c][64][128] in yb until out_proj
  float* sumsq = dtf;        // dtf dead after k_convcum; 8192-row sum(val^2)

  k_cvt_all<<<14720, 256, 0, stream>>>(x, xb, w1, w1b, w2, w2b, nw);

  // in_proj: zx[8192][4384] = xb @ w1b^T (bf16 out + f32 dt copy)
  k_gemm<1><<<dim3(64, 35), 256, 0, stream>>>(xb, w1b, 1024, 4384, 4384,
                                              zxb, nullptr, nullptr, dtf, nullptr);

  k_convcum<<<4096, 256, 0, stream>>>(zxb, cw, cb, xcb, bcb, dtf, dtb, alog, dtv, cumv);

  // merged: k_states (2048 blocks) + k_g halves (128 blocks, also zero sumsq)
  k_ssd1<<<2048 + 128, 256, 0, stream>>>(xcb, bcb, dtv, cumv, SH, Gb, sumsq);
  k_chain<<<256, 512, 0, stream>>>(SH, cumv);
  // k_y fuses the gate: writes gated val to ysb + per-row sumsq
  k_y<<<128 * NCH, 256, 0, stream>>>(xcb, bcb, zxb, dtv, cumv, Gb, SH, Dp, ysb, sumsq);

  // out_proj + fused RMSNorm rowscale + residual: out = scale*(ysb @ w2b^T) + x
  k_gemm<0><<<dim3(64, 8), 256, 0, stream>>>(ysb, w2b, 2048, 1024, 1024,
                                             nullptr, out, x, nullptr, sumsq);

  k_ln<<<8192, 256, 0, stream>>>(out, lw, lb);
}

// Round 15
// 299.067 us; speedup vs baseline: 1.0510x; 1.0510x over previous
//
#include <hip/hip_runtime.h>

typedef unsigned short u16;
typedef unsigned int   u32;

#define L_SEQ    2048
#define D_MODEL  1024
#define D_STATE  128
#define D_INNER  2048
#define NHEADS   32
#define HEADDIM  64
#define CONV_DIM 2304
#define D_IN_PROJ 4384
#define EPSF     1e-5f
#define QC       128        // SSD chunk length
#define NCH      16         // chunks = L_SEQ/QC

using frag  = __attribute__((ext_vector_type(8))) short;
using f32x4 = __attribute__((ext_vector_type(4))) float;
typedef __attribute__((ext_vector_type(8))) unsigned short u16x8;

__device__ __forceinline__ u16 f2bf(float f) {
  u32 u = __float_as_uint(f);
  return (u16)((u + 0x7fffu + ((u >> 16) & 1u)) >> 16);
}
__device__ __forceinline__ float bf2f(u16 u) {
  return __uint_as_float(((u32)u) << 16);
}
__device__ __forceinline__ void async16(const void* g, void* l) {
  __builtin_amdgcn_global_load_lds((const __attribute__((address_space(1))) u32*)g,
                                   (__attribute__((address_space(3))) u32*)l, 16, 0, 0);
}

// ---------------- fused fp32->bf16 converts + W1-tail zero + nw-fold into W2 ----------------
__global__ __launch_bounds__(256) void k_cvt_all(const float* __restrict__ x,
                                                 u16* __restrict__ xb,
                                                 const float* __restrict__ w1,
                                                 u16* __restrict__ w1b,
                                                 const float* __restrict__ w2,
                                                 u16* __restrict__ w2b,
                                                 const float* __restrict__ nw) {
  int bid = blockIdx.x;
  int t = threadIdx.x;
  if (bid >= 12576 && bid < 14624) {
    // W2 path: fold norm_w (per inner-dim column) into the weight
    int i = (bid - 12576) * 256 + t;
    float4 v = ((const float4*)w2)[i];
    float4 wv = *(const float4*)(nw + ((i * 4) & (D_INNER - 1)));
    ushort4 o;
    o.x = f2bf(v.x * wv.x); o.y = f2bf(v.y * wv.y);
    o.z = f2bf(v.z * wv.z); o.w = f2bf(v.w * wv.w);
    ((ushort4*)w2b)[i] = o;
    return;
  }
  const float* src;
  u16* dst;
  int i;
  if (bid < 8192)       { i = bid * 256 + t;          src = x;  dst = xb;  }
  else if (bid < 12576) { i = (bid - 8192) * 256 + t; src = w1; dst = w1b; }
  else {  // zero pad rows 4384..4479 of w1b
    i = (bid - 14624) * 256 + t;
    ((ushort4*)(w1b + (size_t)4384 * 1024))[i] = ushort4{0, 0, 0, 0};
    return;
  }
  float4 v = ((const float4*)src)[i];
  ushort4 o;
  o.x = f2bf(v.x); o.y = f2bf(v.y); o.z = f2bf(v.z); o.w = f2bf(v.w);
  ((ushort4*)dst)[i] = o;
}

// ====== unified GEMM (champion, natural block order): 128x128 tile, 4 waves,
// 2-phase dbuf, vmcnt(4).
// MODE 0: out = rowscale * gemm + resid (out_proj).  MODE 1: bf16 out + f32 dt side-copy.
template <int MODE>
__global__ __launch_bounds__(256) void k_gemm(const u16* __restrict__ A,
                                              const u16* __restrict__ B, int K,
                                              int Nvalid, int ldc,
                                              u16* __restrict__ Cb,
                                              float* __restrict__ Cf,
                                              const float* __restrict__ resid,
                                              float* __restrict__ Cdt,
                                              const float* __restrict__ sumsq) {
  __shared__ __attribute__((aligned(16))) u16 As[2][128 * 32];
  __shared__ __attribute__((aligned(16))) u16 Bs[2][128 * 32];
  const int tid = threadIdx.x;
  const int lane = tid & 63;
  const int wid = tid >> 6;          // 0..3
  const int wm = wid >> 1, wn = wid & 1;
  const int m0 = blockIdx.x * 128, n0 = blockIdx.y * 128;

  f32x4 acc[4][4];
#pragma unroll
  for (int i = 0; i < 4; ++i)
#pragma unroll
    for (int j = 0; j < 4; ++j) acc[i][j] = f32x4{0.f, 0.f, 0.f, 0.f};

  const char* gA[2]; const char* gB[2];
  int cbo[2];
#pragma unroll
  for (int j = 0; j < 2; ++j) {
    int base = (wid * 2 + j) * 1024;
    int p = base + lane * 16;
    int row = p >> 6;
    int colb = p & 63;
    gA[j] = (const char*)A + ((size_t)(m0 + row) * K) * 2 + colb;
    gB[j] = (const char*)B + ((size_t)(n0 + row) * K) * 2 + colb;
    cbo[j] = base;
  }

#define STAGE(bufi, kt) do { size_t kb = (size_t)(kt) * 64; \
    async16(gA[0] + kb, (char*)As[bufi] + cbo[0]); \
    async16(gA[1] + kb, (char*)As[bufi] + cbo[1]); \
    async16(gB[0] + kb, (char*)Bs[bufi] + cbo[0]); \
    async16(gB[1] + kb, (char*)Bs[bufi] + cbo[1]); } while (0)

  const int kg = (lane >> 4) * 16;
  const int rr = wm * 64 + (lane & 15);
  const int cc = wn * 64 + (lane & 15);

  STAGE(0, 0);
  const int nt = K >> 5;
  for (int t = 0; t < nt; ++t) {
    const int cur = t & 1;
    if (t + 1 < nt) {
      STAGE(cur ^ 1, t + 1);
      asm volatile("s_waitcnt vmcnt(4)" ::: "memory");  // oldest 4 (cur buf) landed
    } else {
      asm volatile("s_waitcnt vmcnt(0)" ::: "memory");
    }
    asm volatile("s_barrier" ::: "memory");
    frag af[4], bfr[4];
#pragma unroll
    for (int mi = 0; mi < 4; ++mi)
      af[mi] = *(const frag*)((const char*)As[cur] + (rr + mi * 16) * 64 + kg);
#pragma unroll
    for (int ni = 0; ni < 4; ++ni)
      bfr[ni] = *(const frag*)((const char*)Bs[cur] + (cc + ni * 16) * 64 + kg);
#pragma unroll
    for (int mi = 0; mi < 4; ++mi)
#pragma unroll
      for (int ni = 0; ni < 4; ++ni)
        acc[mi][ni] = __builtin_amdgcn_mfma_f32_16x16x32_bf16(af[mi], bfr[ni],
                                                              acc[mi][ni], 0, 0, 0);
    asm volatile("s_waitcnt lgkmcnt(0)" ::: "memory");
    asm volatile("s_barrier" ::: "memory");
  }
#undef STAGE

  const int er = (lane >> 4) * 4;
  const int ec = lane & 15;
  if (MODE == 1) {
#pragma unroll
    for (int mi = 0; mi < 4; ++mi) {
#pragma unroll
      for (int ni = 0; ni < 4; ++ni) {
        int col = n0 + wn * 64 + ni * 16 + ec;
        if (col < Nvalid) {
#pragma unroll
          for (int r = 0; r < 4; ++r) {
            int row = m0 + wm * 64 + mi * 16 + er + r;
            size_t off = (size_t)row * ldc + col;
            float v = acc[mi][ni][r];
            Cb[off] = f2bf(v);
            if (col >= D_INNER + CONV_DIM)
              Cdt[(size_t)row * NHEADS + (col - D_INNER - CONV_DIM)] = v;
          }
        }
      }
    }
  } else {
#pragma unroll
    for (int mi = 0; mi < 4; ++mi) {
#pragma unroll
      for (int r = 0; r < 4; ++r) {
        int row = m0 + wm * 64 + mi * 16 + er + r;
        float sc = rsqrtf(sumsq[row] * (1.f / D_INNER) + EPSF);
#pragma unroll
        for (int ni = 0; ni < 4; ++ni) {
          int col = n0 + wn * 64 + ni * 16 + ec;
          size_t off = (size_t)row * ldc + col;
          Cf[off] = acc[mi][ni][r] * sc + resid[off];
        }
      }
    }
  }
}

// ---------------- depthwise conv(4)+silu (4-l strips) AND dt/cumsum (merged) ----------------
__global__ __launch_bounds__(256) void k_convcum(const u16* __restrict__ zxb,
                                                 const float* __restrict__ cw,
                                                 const float* __restrict__ cb,
                                                 u16* __restrict__ xcb,
                                                 u16* __restrict__ bcb,
                                                 const float* __restrict__ dtf,
                                                 const float* __restrict__ dtb,
                                                 const float* __restrict__ alog,
                                                 float* __restrict__ dtv,
                                                 float* __restrict__ cumv) {
  int bid = blockIdx.x;
  if (bid < 2048) {
    // conv strip: 4 consecutive l, 7-row register window (halo loaded once)
    int b = bid >> 9;                 // 512 strips per batch
    int l0 = (bid & 511) * 4;
    size_t rowbase = (size_t)b * L_SEQ + l0;
    for (int g = threadIdx.x; g < CONV_DIM / 4; g += 256) {
      int c = g * 4;
      float4 w0 = ((const float4*)cw)[c + 0];
      float4 w1 = ((const float4*)cw)[c + 1];
      float4 w2 = ((const float4*)cw)[c + 2];
      float4 w3 = ((const float4*)cw)[c + 3];
      float4 bias = *(const float4*)(cb + c);
      ushort4 xv[7];
#pragma unroll
      for (int k = 0; k < 7; ++k) {
        int lm = l0 - 3 + k;
        xv[k] = (lm >= 0)
            ? *(const ushort4*)(zxb + (rowbase + (k - 3)) * D_IN_PROJ + D_INNER + c)
            : ushort4{0, 0, 0, 0};
      }
#pragma unroll
      for (int dl = 0; dl < 4; ++dl) {
        float a0 = bias.x, a1 = bias.y, a2 = bias.z, a3 = bias.w;
#pragma unroll
        for (int k = 0; k < 4; ++k) {
          ushort4 v = xv[dl + k];     // row l0+dl-3+k  (zeros below l=0)
          a0 = fmaf(bf2f(v.x), (&w0.x)[k], a0);
          a1 = fmaf(bf2f(v.y), (&w1.x)[k], a1);
          a2 = fmaf(bf2f(v.z), (&w2.x)[k], a2);
          a3 = fmaf(bf2f(v.w), (&w3.x)[k], a3);
        }
        a0 = a0 / (1.f + __expf(-a0));
        a1 = a1 / (1.f + __expf(-a1));
        a2 = a2 / (1.f + __expf(-a2));
        a3 = a3 / (1.f + __expf(-a3));
        ushort4 o;
        o.x = f2bf(a0); o.y = f2bf(a1); o.z = f2bf(a2); o.w = f2bf(a3);
        size_t row = rowbase + dl;
        if (c < D_INNER) {
          *(ushort4*)(xcb + row * D_INNER + c) = o;
        } else {
          *(ushort4*)(bcb + row * 256 + (c - D_INNER)) = o;
        }
      }
    }
    return;
  }
  // dt + in-chunk inclusive cumsum (blocks 2048..4095, threads 0..127 active)
  int cb_ = bid - 2048;            // bh*16 + c
  int c = cb_ & (NCH - 1);
  int bh = cb_ >> 4;
  int h = bh & 31, b = bh >> 5;
  int t = threadIdx.x;
  float x = 0.f, dt = 0.f;
  if (t < 128) {
    int l = c * QC + t;
    float raw = dtf[((size_t)(b * L_SEQ + l)) * NHEADS + h] + dtb[h];
    dt = raw > 20.f ? raw : log1pf(expf(raw));
    float A = -expf(alog[h]);
    x = dt * A;
    int lane = t & 63;
#pragma unroll
    for (int off = 1; off < 64; off <<= 1) {
      float up = __shfl_up(x, off);
      if (lane >= off) x += up;
    }
  }
  __shared__ float wtot;
  if (t == 63) wtot = x;
  __syncthreads();
  if (t < 128) {
    if (t >= 64) x += wtot;
    size_t o = (size_t)bh * L_SEQ + c * QC + t;
    dtv[o] = dt;
    cumv[o] = x;
  }
}

// ========= merged SSD stage 1: k_states (bid<2048) + k_g halves (bid>=2048) =========
__global__ __launch_bounds__(256) void k_ssd1(const u16* __restrict__ xcb,
                                              const u16* __restrict__ bcb,
                                              const float* __restrict__ dtv,
                                              const float* __restrict__ cumv,
                                              u16* __restrict__ SH,
                                              u16* __restrict__ Gb,
                                              float* __restrict__ sumsq) {
  __shared__ __attribute__((aligned(16))) char smem[52736];
  int bid = blockIdx.x;
  int tid = threadIdx.x, lane = tid & 63, wid = tid >> 6;
  int wm = wid >> 1, wn = wid & 1;
  const int er = (lane >> 4) * 4;
  const int ec = lane & 15;

  if (bid < 2048) {
    // -------- states path --------
    u16* XT = (u16*)smem;                    // [64][136]
    u16* BW = (u16*)(smem + 17408);          // [128][136]
    float* wlds = (float*)(smem + 52224);    // [128]
    int c = bid & (NCH - 1);
    int bh = bid >> 4;
    int h = bh & 31, b = bh >> 5;
    int l0 = c * QC;
    size_t bhl = (size_t)bh * L_SEQ + l0;
    if (tid < 128) {
      float ce = cumv[bhl + 127];
      wlds[tid] = __expf(ce - cumv[bhl + tid]) * dtv[bhl + tid];
    }
    const int jrow = tid & 127;
    const u16* xbase = xcb + ((size_t)(b * L_SEQ + l0)) * D_INNER + h * HEADDIM;
    {
      int sb = (tid >> 7) * 4;
#pragma unroll
      for (int s = 0; s < 4; ++s) {
        int seg = sb + s;
        u16x8 xv = *(const u16x8*)(xbase + (size_t)jrow * D_INNER + seg * 8);
#pragma unroll
        for (int k = 0; k < 8; ++k) XT[(seg * 8 + k) * 136 + jrow] = xv[k];
      }
    }
    __syncthreads();
    const u16* bbase = bcb + (size_t)(b * L_SEQ + l0) * 256;
    {
      int sb = (tid >> 7) * 8;
      float w = wlds[jrow];
#pragma unroll
      for (int s = 0; s < 8; ++s) {
        int seg = sb + s;
        u16x8 bv = *(const u16x8*)(bbase + (size_t)jrow * 256 + seg * 8);
#pragma unroll
        for (int k = 0; k < 8; ++k)
          BW[(seg * 8 + k) * 136 + jrow] = f2bf(bf2f(bv[k]) * w);
      }
    }
    __syncthreads();
    f32x4 acc[2][4];
#pragma unroll
    for (int i = 0; i < 2; ++i)
#pragma unroll
      for (int j = 0; j < 4; ++j) acc[i][j] = f32x4{0.f, 0.f, 0.f, 0.f};
    int rr = wm * 32 + (lane & 15);
    int cc = wn * 64 + (lane & 15);
    __builtin_amdgcn_s_setprio(1);
#pragma unroll
    for (int kk = 0; kk < 4; ++kk) {
      int ko = kk * 32 + (lane >> 4) * 8;
      frag af[2], bfr[4];
#pragma unroll
      for (int mi = 0; mi < 2; ++mi)
        af[mi] = *(const frag*)&XT[(rr + mi * 16) * 136 + ko];
#pragma unroll
      for (int ni = 0; ni < 4; ++ni)
        bfr[ni] = *(const frag*)&BW[(cc + ni * 16) * 136 + ko];
#pragma unroll
      for (int mi = 0; mi < 2; ++mi)
#pragma unroll
        for (int ni = 0; ni < 4; ++ni)
          acc[mi][ni] = __builtin_amdgcn_mfma_f32_16x16x32_bf16(af[mi], bfr[ni],
                                                                acc[mi][ni], 0, 0, 0);
    }
    __builtin_amdgcn_s_setprio(0);
    u16* sbase = SH + ((size_t)(bh * NCH + c)) * (64 * 128);
#pragma unroll
    for (int mi = 0; mi < 2; ++mi)
#pragma unroll
      for (int ni = 0; ni < 4; ++ni)
#pragma unroll
        for (int r = 0; r < 4; ++r) {
          int p = wm * 32 + mi * 16 + er + r;
          int n = wn * 64 + ni * 16 + ec;
          sbase[(size_t)p * 128 + n] = f2bf(acc[mi][ni][r]);
        }
  } else {
    // -------- G path: half of one (b,chunk): G rows half*64..+63 --------
    u16* Cs = (u16*)smem;                    // [64][136]
    u16* Bs = (u16*)(smem + 17408);          // [128][136]
    int gbid = bid - 2048;                   // (b*16 + c)*2 + half
    if (gbid < 32) sumsq[gbid * 256 + tid] = 0.f;   // zero 8192-row accumulator
    int half = gbid & 1;
    int c = (gbid >> 1) & (NCH - 1);
    int b = gbid >> 5;
    const u16* base = bcb + (size_t)(b * L_SEQ + c * QC) * 256;
    for (int idx = tid; idx < 128 * 16; idx += 256) {
      int j = idx >> 4, seg = idx & 15;
      *(u16x8*)&Bs[j * 136 + seg * 8] = *(const u16x8*)(base + (size_t)j * 256 + seg * 8);
    }
    for (int idx = tid; idx < 64 * 16; idx += 256) {
      int i = idx >> 4, seg = idx & 15;
      *(u16x8*)&Cs[i * 136 + seg * 8] =
          *(const u16x8*)(base + (size_t)(half * 64 + i) * 256 + 128 + seg * 8);
    }
    __syncthreads();
    f32x4 acc[2][4];
#pragma unroll
    for (int i = 0; i < 2; ++i)
#pragma unroll
      for (int j = 0; j < 4; ++j) acc[i][j] = f32x4{0.f, 0.f, 0.f, 0.f};
    int rr = wm * 32 + (lane & 15);
    int cc = wn * 64 + (lane & 15);
    __builtin_amdgcn_s_setprio(1);
#pragma unroll
    for (int kk = 0; kk < 4; ++kk) {
      int ko = kk * 32 + (lane >> 4) * 8;
      frag af[2], bfr[4];
#pragma unroll
      for (int mi = 0; mi < 2; ++mi)
        af[mi] = *(const frag*)&Cs[(rr + mi * 16) * 136 + ko];
#pragma unroll
      for (int ni = 0; ni < 4; ++ni)
        bfr[ni] = *(const frag*)&Bs[(cc + ni * 16) * 136 + ko];
#pragma unroll
      for (int mi = 0; mi < 2; ++mi)
#pragma unroll
        for (int ni = 0; ni < 4; ++ni)
          acc[mi][ni] = __builtin_amdgcn_mfma_f32_16x16x32_bf16(af[mi], bfr[ni],
                                                                acc[mi][ni], 0, 0, 0);
    }
    __builtin_amdgcn_s_setprio(0);
    u16* gbase = Gb + ((size_t)(b * NCH + c)) * 128 * 128;
#pragma unroll
    for (int mi = 0; mi < 2; ++mi)
#pragma unroll
      for (int ni = 0; ni < 4; ++ni)
#pragma unroll
        for (int r = 0; r < 4; ++r) {
          int i = half * 64 + wm * 32 + mi * 16 + er + r;
          int j = wn * 64 + ni * 16 + ec;
          gbase[(size_t)i * 128 + j] = f2bf(acc[mi][ni][r]);
        }
  }
}

// ---------------- inter-chunk chain (in place), prefetched ----------------
__global__ __launch_bounds__(512) void k_chain(u16* __restrict__ SH,
                                               const float* __restrict__ cumv) {
  int bid = blockIdx.x;
  int half = bid & 1;
  int bh = bid >> 1;
  int t = threadIdx.x;
  u16* base = SH + (size_t)bh * NCH * 8192 + half * 4096 + t * 8;
  float H[8];
#pragma unroll
  for (int i = 0; i < 8; ++i) H[i] = 0.f;
  u16x8 s = *(const u16x8*)base;
  float e = __expf(cumv[(size_t)bh * L_SEQ + 127]);
  for (int c = 0; c < NCH; ++c) {
    u16x8 cs = s;
    float ce = e;
    if (c + 1 < NCH) {
      s = *(const u16x8*)(base + (size_t)(c + 1) * 8192);
      e = __expf(cumv[(size_t)bh * L_SEQ + (c + 1) * QC + 127]);
    }
    u16x8 h0;
#pragma unroll
    for (int k = 0; k < 8; ++k) h0[k] = f2bf(H[k]);
    *(u16x8*)(base + (size_t)c * 8192) = h0;
#pragma unroll
    for (int k = 0; k < 8; ++k) H[k] = fmaf(H[k], ce, bf2f(cs[k]));
  }
}

// ---------------- Y = M@X^T + exp(cum_i)*(C@H^T), then FUSED gate ----------------
__global__ __launch_bounds__(256) void k_y(const u16* __restrict__ xcb,
                                           const u16* __restrict__ bcb,
                                           const u16* __restrict__ zxb,
                                           const float* __restrict__ dtv,
                                           const float* __restrict__ cumv,
                                           const u16* __restrict__ Gb,
                                           const u16* __restrict__ SH,
                                           const float* __restrict__ Dp,
                                           u16* __restrict__ ysb,
                                           float* __restrict__ sumsq) {
  __shared__ u16 Abuf[128 * 136];
  __shared__ u16 Bbuf[64 * 136];
  __shared__ float cums[128], dts[128];
  float* rowsq = dts;                 // dts dead after mask phase; reuse for row sums
  int bid = blockIdx.x;
  int c = bid & (NCH - 1);
  int bh = bid >> 4;
  int h = bh & 31, b = bh >> 5;
  int tid = threadIdx.x, lane = tid & 63, wid = tid >> 6;
  int wm = wid >> 1, wn = wid & 1;
  int l0 = c * QC;
  size_t bhl = (size_t)bh * L_SEQ + l0;
  if (tid < 128) { cums[tid] = cumv[bhl + tid]; dts[tid] = dtv[bhl + tid]; }
  const u16* xbase = xcb + ((size_t)(b * L_SEQ + l0)) * D_INNER + h * HEADDIM;
  {
    int jrow = tid & 127;
    int sb = (tid >> 7) * 4;
#pragma unroll
    for (int s = 0; s < 4; ++s) {
      int seg = sb + s;
      u16x8 xv = *(const u16x8*)(xbase + (size_t)jrow * D_INNER + seg * 8);
#pragma unroll
      for (int k = 0; k < 8; ++k) Bbuf[(seg * 8 + k) * 136 + jrow] = xv[k];
    }
  }
  __syncthreads();
  const u16* gbase = Gb + ((size_t)(b * NCH + c)) * 128 * 128;
  for (int idx = tid; idx < 128 * 16; idx += 256) {
    int i = idx >> 4, seg = idx & 15;
    int j0 = seg * 8;
    u16x8 o;
    if (j0 > i) {
#pragma unroll
      for (int k = 0; k < 8; ++k) o[k] = 0;
    } else {
      u16x8 g = *(const u16x8*)(gbase + (size_t)i * 128 + j0);
      float ci = cums[i];
#pragma unroll
      for (int k = 0; k < 8; ++k) {
        int j = j0 + k;
        float m = (j <= i) ? bf2f(g[k]) * __expf(ci - cums[j]) * dts[j] : 0.f;
        o[k] = f2bf(m);
      }
    }
    *(u16x8*)&Abuf[i * 136 + j0] = o;
  }
  __syncthreads();
  f32x4 acc1[4][2], acc2[4][2];
#pragma unroll
  for (int i = 0; i < 4; ++i)
#pragma unroll
    for (int j = 0; j < 2; ++j) {
      acc1[i][j] = f32x4{0.f, 0.f, 0.f, 0.f};
      acc2[i][j] = f32x4{0.f, 0.f, 0.f, 0.f};
    }
  int rr = wm * 64 + (lane & 15);
  int cc = wn * 32 + (lane & 15);
  __builtin_amdgcn_s_setprio(1);
#pragma unroll
  for (int kk = 0; kk < 4; ++kk) {
    int ko = kk * 32 + (lane >> 4) * 8;
    frag af[4], bfr[2];
#pragma unroll
    for (int mi = 0; mi < 4; ++mi)
      af[mi] = *(const frag*)&Abuf[(rr + mi * 16) * 136 + ko];
#pragma unroll
    for (int ni = 0; ni < 2; ++ni)
      bfr[ni] = *(const frag*)&Bbuf[(cc + ni * 16) * 136 + ko];
#pragma unroll
    for (int mi = 0; mi < 4; ++mi)
#pragma unroll
      for (int ni = 0; ni < 2; ++ni)
        acc1[mi][ni] = __builtin_amdgcn_mfma_f32_16x16x32_bf16(af[mi], bfr[ni],
                                                               acc1[mi][ni], 0, 0, 0);
  }
  __builtin_amdgcn_s_setprio(0);
  __syncthreads();
  // capture X values for the epilogue from Bbuf (X^T) BEFORE it is overwritten by H.
  const int er = (lane >> 4) * 4;
  const int ec = lane & 15;
  u16 xr[4][4][2];
#pragma unroll
  for (int mi = 0; mi < 4; ++mi)
#pragma unroll
    for (int r = 0; r < 4; ++r) {
      int i = wm * 64 + mi * 16 + er + r;
#pragma unroll
      for (int ni = 0; ni < 2; ++ni) {
        int p = wn * 32 + ni * 16 + ec;
        xr[mi][r][ni] = Bbuf[p * 136 + i];
      }
    }
  __syncthreads();   // captures complete before overwrite
  const u16* cbase = bcb + (size_t)(b * L_SEQ + l0) * 256 + 128;
  for (int idx = tid; idx < 128 * 16; idx += 256) {
    int i = idx >> 4, seg = idx & 15;
    *(u16x8*)&Abuf[i * 136 + seg * 8] = *(const u16x8*)(cbase + (size_t)i * 256 + seg * 8);
  }
  const u16* hbase = SH + ((size_t)(bh * NCH + c)) * (64 * 128);
  for (int idx = tid; idx < 64 * 16; idx += 256) {
    int p = idx >> 4, seg = idx & 15;
    *(u16x8*)&Bbuf[p * 136 + seg * 8] = *(const u16x8*)(hbase + (size_t)p * 128 + seg * 8);
  }
  __syncthreads();
  if (tid < 128) rowsq[tid] = 0.f;    // dts no longer needed; zero row accumulators
  __builtin_amdgcn_s_setprio(1);
#pragma unroll
  for (int kk = 0; kk < 4; ++kk) {
    int ko = kk * 32 + (lane >> 4) * 8;
    frag af[4], bfr[2];
#pragma unroll
    for (int mi = 0; mi < 4; ++mi)
      af[mi] = *(const frag*)&Abuf[(rr + mi * 16) * 136 + ko];
#pragma unroll
    for (int ni = 0; ni < 2; ++ni)
      bfr[ni] = *(const frag*)&Bbuf[(cc + ni * 16) * 136 + ko];
#pragma unroll
    for (int mi = 0; mi < 4; ++mi)
#pragma unroll
      for (int ni = 0; ni < 2; ++ni)
        acc2[mi][ni] = __builtin_amdgcn_mfma_f32_16x16x32_bf16(af[mi], bfr[ni],
                                                               acc2[mi][ni], 0, 0, 0);
  }
  __builtin_amdgcn_s_setprio(0);
  __syncthreads();                    // rowsq zeroed + all MFMAs done before atomics
  const float Dh = Dp[h];
#pragma unroll
  for (int mi = 0; mi < 4; ++mi)
#pragma unroll
    for (int r = 0; r < 4; ++r) {
      int i = wm * 64 + mi * 16 + er + r;
      size_t grow = (size_t)(b * L_SEQ + l0 + i);
      float e = __expf(cums[i]);
      float part = 0.f;
#pragma unroll
      for (int ni = 0; ni < 2; ++ni) {
        int p = wn * 32 + ni * 16 + ec;
        float acc = acc1[mi][ni][r] + e * acc2[mi][ni][r];
        float xv = bf2f(xr[mi][r][ni]);
        float zz = bf2f(zxb[grow * D_IN_PROJ + h * HEADDIM + p]);
        float val = (acc + Dh * xv) * (zz / (1.f + __expf(-zz)));
        ysb[grow * D_INNER + h * HEADDIM + p] = f2bf(val);
        part += val * val;
      }
      part += __shfl_xor(part, 1);
      part += __shfl_xor(part, 2);
      part += __shfl_xor(part, 4);
      part += __shfl_xor(part, 8);
      if ((lane & 15) == 0) atomicAdd(&rowsq[i], part);
    }
  __syncthreads();
  if (tid < 128) atomicAdd(&sumsq[(size_t)b * L_SEQ + l0 + tid], rowsq[tid]);
}

// ---------------- final LayerNorm (in-place on d_out) ----------------
union F4 { float4 v; float f[4]; };
__global__ __launch_bounds__(256) void k_ln(float* __restrict__ io,
                                            const float* __restrict__ lw,
                                            const float* __restrict__ lb) {
  int row = blockIdx.x;
  int t = threadIdx.x;
  int d0 = t * 4;
  F4 v; v.v = *(const float4*)(io + (size_t)row * D_MODEL + d0);
  float s1 = v.f[0] + v.f[1] + v.f[2] + v.f[3];
  float s2 = v.f[0] * v.f[0] + v.f[1] * v.f[1] + v.f[2] * v.f[2] + v.f[3] * v.f[3];
  __shared__ float r1[4], r2[4];
#pragma unroll
  for (int off = 32; off; off >>= 1) {
    s1 += __shfl_xor(s1, off);
    s2 += __shfl_xor(s2, off);
  }
  if ((t & 63) == 0) { r1[t >> 6] = s1; r2[t >> 6] = s2; }
  __syncthreads();
  float S1 = r1[0] + r1[1] + r1[2] + r1[3];
  float S2 = r2[0] + r2[1] + r2[2] + r2[3];
  float mu = S1 * (1.f / D_MODEL);
  float var = S2 * (1.f / D_MODEL) - mu * mu;
  float inv = rsqrtf(var + EPSF);
  F4 w, bb, o;
  w.v = *(const float4*)(lw + d0);
  bb.v = *(const float4*)(lb + d0);
#pragma unroll
  for (int c = 0; c < 4; ++c) o.f[c] = (v.f[c] - mu) * inv * w.f[c] + bb.f[c];
  *(float4*)(io + (size_t)row * D_MODEL + d0) = o.v;
}

extern "C" void kernel_launch(void* const* d_in, const int* in_sizes, int n_in,
                              void* d_out, int out_size, void* d_ws, size_t ws_size,
                              hipStream_t stream) {
  const float* x    = (const float*)d_in[0];
  const float* w1   = (const float*)d_in[1];
  const float* cw   = (const float*)d_in[2];
  const float* cb   = (const float*)d_in[3];
  const float* dtb  = (const float*)d_in[4];
  const float* alog = (const float*)d_in[5];
  const float* Dp   = (const float*)d_in[6];
  const float* nw   = (const float*)d_in[7];
  const float* w2   = (const float*)d_in[8];
  const float* lw   = (const float*)d_in[9];
  const float* lb   = (const float*)d_in[10];
  float* out = (float*)d_out;
  char* ws = (char*)d_ws;

  // workspace layout (bytes)
  u16*   xb   = (u16*)(ws + 0);            // 8192x1024 bf16  16,777,216
  u16*   w1b  = (u16*)(ws + 16777216);     // 4480x1024 bf16   9,175,040
  u16*   w2b  = (u16*)(ws + 25952256);     // 1024x2048 bf16   4,194,304
  u16*   zxb  = (u16*)(ws + 30146560);     // 8192x4384 bf16  71,827,456
  u16*   xcb  = (u16*)(ws + 101974016);    // 8192x2048 bf16  33,554,432
  float* dtf  = (float*)(ws + 135528448);  // 8192x32 f32      1,048,576
  float* dtv  = (float*)(ws + 136577024);  // 128x2048 f32     1,048,576
  float* cumv = (float*)(ws + 137625600);  // 128x2048 f32     1,048,576
  u16*   ysb  = (u16*)(ws + 138674176);    // 8192x2048 bf16  33,554,432
  u16*   yb   = (u16*)(ws + 172228608);    // 8192x2048 bf16  33,554,432
  u16*   Gb   = (u16*)(ws + 205783040);    // 64x128x128 bf16  4,194,304
  // total: 209,977,344 (proven available)
  if (ws_size < (size_t)209977344) return;

  u16* bcb = (u16*)out;      // d_out as B/C bf16 scratch (8192x256) until out_proj
  u16* SH  = yb;             // chunk states bf16 [bh][c][64][128] in yb until out_proj
  float* sumsq = dtf;        // dtf dead after k_convcum; 8192-row sum(val^2)

  k_cvt_all<<<14720, 256, 0, stream>>>(x, xb, w1, w1b, w2, w2b, nw);

  // in_proj: zx[8192][4384] = xb @ w1b^T (bf16 out + f32 dt copy)
  k_gemm<1><<<dim3(64, 35), 256, 0, stream>>>(xb, w1b, 1024, 4384, 4384,
                                              zxb, nullptr, nullptr, dtf, nullptr);

  k_convcum<<<4096, 256, 0, stream>>>(zxb, cw, cb, xcb, bcb, dtf, dtb, alog, dtv, cumv);

  // merged: k_states (2048 blocks) + k_g halves (128 blocks, also zero sumsq)
  k_ssd1<<<2048 + 128, 256, 0, stream>>>(xcb, bcb, dtv, cumv, SH, Gb, sumsq);
  k_chain<<<256, 512, 0, stream>>>(SH, cumv);
  // k_y fuses the gate: writes gated val to ysb + per-row sumsq
  k_y<<<128 * NCH, 256, 0, stream>>>(xcb, bcb, zxb, dtv, cumv, Gb, SH, Dp, ysb, sumsq);

  // out_proj + fused RMSNorm rowscale + residual: out = scale*(ysb @ w2b^T) + x
  k_gemm<0><<<dim3(64, 8), 256, 0, stream>>>(ysb, w2b, 2048, 1024, 1024,
                                             nullptr, out, x, nullptr, sumsq);

  k_ln<<<8192, 256, 0, stream>>>(out, lw, lb);
}